// Round 1
// baseline (1081.996 us; speedup 1.0000x reference)
//
#include <hip/hip_runtime.h>
#include <hip/hip_bf16.h>

#define N_NODES 50000
#define N_EDGES 800000
#define IN_F 256
#define OUT_F 32
#define NHEAD 8
#define HD 256      // NHEAD*OUT_F
#define EDGE_F 32
#define N_ETYPES 8
#define NEG_SLOPE 0.1f

// order-preserving float -> unsigned key (monotone), for atomicMax on floats
__device__ __forceinline__ unsigned fkey(float f) {
    unsigned b = __float_as_uint(f);
    return b ^ ((unsigned)((int)b >> 31) | 0x80000000u);
}
__device__ __forceinline__ float fdec(unsigned k) {
    unsigned b = (k & 0x80000000u) ? (k ^ 0x80000000u) : ~k;
    return __uint_as_float(b);
}

// ---- tiny: he[t][hh] = sum_f a_e[hh,f] * (edge_emb @ W_e)[t, hh*32+f] ----
__global__ void edge_he_kernel(const float* __restrict__ edge_emb,
                               const float* __restrict__ W_e,
                               const float* __restrict__ a_e,
                               float* __restrict__ he) {
    int tid = threadIdx.x;
    if (tid >= N_ETYPES * NHEAD) return;
    int t = tid / NHEAD, hh = tid % NHEAD;
    float acc = 0.f;
    for (int f = 0; f < EDGE_F; ++f) {
        float ev = 0.f;
        for (int k = 0; k < EDGE_F; ++k)
            ev += edge_emb[t * EDGE_F + k] * W_e[k * (EDGE_F * NHEAD) + hh * EDGE_F + f];
        acc += a_e[hh * EDGE_F + f] * ev;
    }
    he[t * NHEAD + hh] = acc;
}

// ---- h = x @ W  (fp32, 64x64 tile, 4x4 microtile), NaN guard ----
__global__ __launch_bounds__(256) void gemm_h(const float* __restrict__ x,
                                              const float* __restrict__ W,
                                              float* __restrict__ h) {
    __shared__ float As[32][64];   // As[k][m] (transposed x tile)
    __shared__ float Bs[32][64];   // Bs[k][n]
    const int row0 = blockIdx.x * 64;
    const int col0 = blockIdx.y * 64;
    const int tid = threadIdx.x;
    const int tr = tid / 16, tc = tid % 16;
    float acc[4][4] = {};
    const int am = tid >> 2;           // 0..63 (row within tile)
    const int akq = (tid & 3) * 8;     // 0,8,16,24 (k start)
    const int bk = tid >> 3;           // 0..31
    const int bnq = (tid & 7) * 8;     // 0..56

    for (int k0 = 0; k0 < IN_F; k0 += 32) {
        int grow = row0 + am;
        float4 va0, va1;
        if (grow < N_NODES) {
            va0 = *(const float4*)&x[grow * IN_F + k0 + akq];
            va1 = *(const float4*)&x[grow * IN_F + k0 + akq + 4];
        } else {
            va0 = make_float4(0.f, 0.f, 0.f, 0.f); va1 = va0;
        }
        As[akq + 0][am] = va0.x; As[akq + 1][am] = va0.y;
        As[akq + 2][am] = va0.z; As[akq + 3][am] = va0.w;
        As[akq + 4][am] = va1.x; As[akq + 5][am] = va1.y;
        As[akq + 6][am] = va1.z; As[akq + 7][am] = va1.w;

        float4 vb0 = *(const float4*)&W[(k0 + bk) * HD + col0 + bnq];
        float4 vb1 = *(const float4*)&W[(k0 + bk) * HD + col0 + bnq + 4];
        *(float4*)&Bs[bk][bnq] = vb0;
        *(float4*)&Bs[bk][bnq + 4] = vb1;
        __syncthreads();

        #pragma unroll
        for (int k = 0; k < 32; ++k) {
            float4 a4 = *(float4*)&As[k][tr * 4];
            float4 b4 = *(float4*)&Bs[k][tc * 4];
            float av[4] = {a4.x, a4.y, a4.z, a4.w};
            float bv[4] = {b4.x, b4.y, b4.z, b4.w};
            #pragma unroll
            for (int i = 0; i < 4; ++i)
                #pragma unroll
                for (int j = 0; j < 4; ++j)
                    acc[i][j] += av[i] * bv[j];
        }
        __syncthreads();
    }
    #pragma unroll
    for (int i = 0; i < 4; ++i) {
        int grow = row0 + tr * 4 + i;
        if (grow < N_NODES) {
            float vals[4];
            #pragma unroll
            for (int j = 0; j < 4; ++j) {
                float v = acc[i][j];
                vals[j] = (v != v) ? 0.f : v;   // NaN guard as in reference
            }
            *(float4*)&h[grow * HD + col0 + tc * 4] =
                make_float4(vals[0], vals[1], vals[2], vals[3]);
        }
    }
}

// ---- hl[n,hh] = a_l[hh,:].h[n,hh,:],  hr likewise ----
__global__ __launch_bounds__(256) void node_logits(const float* __restrict__ h,
                                                   const float* __restrict__ a_l,
                                                   const float* __restrict__ a_r,
                                                   float* __restrict__ hl,
                                                   float* __restrict__ hr) {
    __shared__ float sal[HD], sar[HD];
    int tid = threadIdx.x;
    sal[tid] = a_l[tid];
    sar[tid] = a_r[tid];
    __syncthreads();
    int idx = blockIdx.x * 256 + tid;
    if (idx >= N_NODES * NHEAD) return;
    int n = idx >> 3, hh = idx & 7;
    const float* hp = h + (size_t)n * HD + hh * OUT_F;
    float al = 0.f, ar = 0.f;
    #pragma unroll
    for (int d = 0; d < OUT_F; d += 4) {
        float4 v = *(const float4*)&hp[d];
        float4 l = *(const float4*)&sal[hh * OUT_F + d];
        float4 r = *(const float4*)&sar[hh * OUT_F + d];
        al += v.x * l.x + v.y * l.y + v.z * l.z + v.w * l.w;
        ar += v.x * r.x + v.y * r.y + v.z * r.z + v.w * r.w;
    }
    hl[idx] = al;
    hr[idx] = ar;
}

// ---- per-edge logits + segment max (atomic on encoded key) ----
__global__ __launch_bounds__(256) void edge_max(const int* __restrict__ row,
                                                const int* __restrict__ col,
                                                const int* __restrict__ tp,
                                                const float* __restrict__ hl,
                                                const float* __restrict__ hr,
                                                const float* __restrict__ he,
                                                unsigned* __restrict__ mu) {
    int e = blockIdx.x * 256 + threadIdx.x;
    if (e >= N_EDGES) return;
    int r = row[e], c = col[e], t = tp[e];
    float4 l0 = *(const float4*)&hl[r * 8], l1 = *(const float4*)&hl[r * 8 + 4];
    float4 r0 = *(const float4*)&hr[c * 8], r1 = *(const float4*)&hr[c * 8 + 4];
    float4 e0 = *(const float4*)&he[t * 8], e1 = *(const float4*)&he[t * 8 + 4];
    float s[8] = {l0.x + r0.x + e0.x, l0.y + r0.y + e0.y,
                  l0.z + r0.z + e0.z, l0.w + r0.w + e0.w,
                  l1.x + r1.x + e1.x, l1.y + r1.y + e1.y,
                  l1.z + r1.z + e1.z, l1.w + r1.w + e1.w};
    #pragma unroll
    for (int hh = 0; hh < 8; ++hh) {
        float v = s[hh] > 0.f ? s[hh] : NEG_SLOPE * s[hh];
        atomicMax(&mu[c * 8 + hh], fkey(v));
    }
}

// ---- ex = exp(s - m[col]); z[col] += ex; store ex ----
__global__ __launch_bounds__(256) void edge_exp(const int* __restrict__ row,
                                                const int* __restrict__ col,
                                                const int* __restrict__ tp,
                                                const float* __restrict__ hl,
                                                const float* __restrict__ hr,
                                                const float* __restrict__ he,
                                                const unsigned* __restrict__ mu,
                                                float* __restrict__ ex,
                                                float* __restrict__ z) {
    int e = blockIdx.x * 256 + threadIdx.x;
    if (e >= N_EDGES) return;
    int r = row[e], c = col[e], t = tp[e];
    float4 l0 = *(const float4*)&hl[r * 8], l1 = *(const float4*)&hl[r * 8 + 4];
    float4 r0 = *(const float4*)&hr[c * 8], r1 = *(const float4*)&hr[c * 8 + 4];
    float4 e0 = *(const float4*)&he[t * 8], e1 = *(const float4*)&he[t * 8 + 4];
    float s[8] = {l0.x + r0.x + e0.x, l0.y + r0.y + e0.y,
                  l0.z + r0.z + e0.z, l0.w + r0.w + e0.w,
                  l1.x + r1.x + e1.x, l1.y + r1.y + e1.y,
                  l1.z + r1.z + e1.z, l1.w + r1.w + e1.w};
    float exv[8];
    #pragma unroll
    for (int hh = 0; hh < 8; ++hh) {
        float v = s[hh] > 0.f ? s[hh] : NEG_SLOPE * s[hh];
        float m = fdec(mu[c * 8 + hh]);
        exv[hh] = expf(v - m);
        atomicAdd(&z[c * 8 + hh], exv[hh]);
    }
    *(float4*)&ex[e * 8]     = make_float4(exv[0], exv[1], exv[2], exv[3]);
    *(float4*)&ex[e * 8 + 4] = make_float4(exv[4], exv[5], exv[6], exv[7]);
}

// ---- CSR build ----
__global__ void calc_deg(const int* __restrict__ col, int* __restrict__ deg) {
    int e = blockIdx.x * 256 + threadIdx.x;
    if (e < N_EDGES) atomicAdd(&deg[col[e]], 1);
}

__global__ void scan1(const int* __restrict__ deg, int* __restrict__ excl,
                      int* __restrict__ bsums, int n) {
    __shared__ int sm[256];
    int tid = threadIdx.x;
    int i = blockIdx.x * 256 + tid;
    int v = (i < n) ? deg[i] : 0;
    sm[tid] = v;
    __syncthreads();
    int acc = v;
    for (int off = 1; off < 256; off <<= 1) {
        int add = (tid >= off) ? sm[tid - off] : 0;
        __syncthreads();
        acc += add;
        sm[tid] = acc;
        __syncthreads();
    }
    if (i < n) excl[i] = acc - v;
    if (tid == 255) bsums[blockIdx.x] = acc;
}

__global__ void scan2(int* __restrict__ bsums, int nb) {
    __shared__ int sm[256];
    int tid = threadIdx.x;
    int v = (tid < nb) ? bsums[tid] : 0;
    sm[tid] = v;
    __syncthreads();
    int acc = v;
    for (int off = 1; off < 256; off <<= 1) {
        int add = (tid >= off) ? sm[tid - off] : 0;
        __syncthreads();
        acc += add;
        sm[tid] = acc;
        __syncthreads();
    }
    if (tid < nb) bsums[tid] = acc - v;   // exclusive
}

__global__ void scan3(int* __restrict__ offs, const int* __restrict__ bsums,
                      int n, int total) {
    int i = blockIdx.x * 256 + threadIdx.x;
    if (i < n) offs[i] += bsums[blockIdx.x];
    if (i == 0) offs[n] = total;
}

__global__ void scatter_edges(const int* __restrict__ col,
                              const int* __restrict__ offs,
                              int* __restrict__ cursor,
                              int* __restrict__ esort) {
    int e = blockIdx.x * 256 + threadIdx.x;
    if (e < N_EDGES) {
        int c = col[e];
        int pos = atomicAdd(&cursor[c], 1);
        esort[offs[c] + pos] = e;
    }
}

// ---- aggregation: one wave per node; att written in place over ex ----
__global__ __launch_bounds__(256) void aggregate(const int* __restrict__ offs,
                                                 const int* __restrict__ esort,
                                                 const int* __restrict__ row,
                                                 const float* __restrict__ z,
                                                 const float* __restrict__ h,
                                                 float* __restrict__ out,
                                                 float* __restrict__ exatt) {
    int wid = threadIdx.x >> 6;
    int lane = threadIdx.x & 63;
    int n = blockIdx.x * 4 + wid;
    if (n >= N_NODES) return;
    int hh = lane >> 3;              // head 0..7
    int dsub = (lane & 7) * 4;       // dim group within head
    int beg = offs[n], end = offs[n + 1];
    float zv = z[n * 8 + hh];
    float zinv = 1.0f / zv;          // unused if no edges
    float4 acc = make_float4(0.f, 0.f, 0.f, 0.f);
    for (int j = beg; j < end; ++j) {
        int eid = esort[j];
        int r = row[eid];
        float exv = exatt[eid * 8 + hh];
        float a = exv * zinv;
        if ((lane & 7) == 0) exatt[eid * 8 + hh] = a;   // att output in place
        const float4 hv = *(const float4*)&h[(size_t)r * HD + hh * OUT_F + dsub];
        acc.x += a * hv.x; acc.y += a * hv.y;
        acc.z += a * hv.z; acc.w += a * hv.w;
    }
    *(float4*)&out[(size_t)n * HD + hh * OUT_F + dsub] = acc;
}

extern "C" void kernel_launch(void* const* d_in, const int* in_sizes, int n_in,
                              void* d_out, int out_size, void* d_ws, size_t ws_size,
                              hipStream_t stream) {
    const float* x        = (const float*)d_in[0];
    const float* W        = (const float*)d_in[1];
    const float* W_e      = (const float*)d_in[2];
    const float* edge_emb = (const float*)d_in[3];
    const float* a_l      = (const float*)d_in[4];
    const float* a_r      = (const float*)d_in[5];
    const float* a_e      = (const float*)d_in[6];
    const int*   row      = (const int*)d_in[7];
    const int*   col      = (const int*)d_in[8];
    const int*   tp       = (const int*)d_in[9];

    float* out = (float*)d_out;                       // [N, 256]
    float* exatt = out + (size_t)N_NODES * HD;        // [E, 8]: ex, then att in place

    // workspace layout (floats)
    float*    h      = (float*)d_ws;                  // 12,800,000
    float*    hl     = h + 12800000;                  //    400,000
    float*    hr     = hl + 400000;                   //    400,000
    float*    he     = hr + 400000;                   //         64
    float*    z      = he + 64;                       //    400,000  [zeroed]
    unsigned* mu     = (unsigned*)(z + 400000);       //    400,000  [zeroed]
    int*      deg    = (int*)(mu + 400000);           //     50,000  [zeroed]
    int*      cursor = deg + 50000;                   //     50,000  [zeroed]
    int*      offs   = cursor + 50000;                //     50,001
    int*      bsums  = offs + 50001;                  //        256
    int*      esort  = bsums + 256;                   //    800,000

    // zero z, mu, deg, cursor in one shot (contiguous)
    hipMemsetAsync(z, 0, (size_t)(400000 + 400000 + 50000 + 50000) * 4, stream);

    edge_he_kernel<<<1, 64, 0, stream>>>(edge_emb, W_e, a_e, he);

    dim3 ggrid((N_NODES + 63) / 64, 4);
    gemm_h<<<ggrid, 256, 0, stream>>>(x, W, h);

    node_logits<<<(N_NODES * NHEAD + 255) / 256, 256, 0, stream>>>(h, a_l, a_r, hl, hr);

    const int EB = (N_EDGES + 255) / 256;   // 3125
    calc_deg<<<EB, 256, 0, stream>>>(col, deg);

    const int NB = (N_NODES + 255) / 256;   // 196
    scan1<<<NB, 256, 0, stream>>>(deg, offs, bsums, N_NODES);
    scan2<<<1, 256, 0, stream>>>(bsums, NB);
    scan3<<<NB, 256, 0, stream>>>(offs, bsums, N_NODES, N_EDGES);
    scatter_edges<<<EB, 256, 0, stream>>>(col, offs, cursor, esort);

    edge_max<<<EB, 256, 0, stream>>>(row, col, tp, hl, hr, he, mu);
    edge_exp<<<EB, 256, 0, stream>>>(row, col, tp, hl, hr, he, mu, exatt, z);

    aggregate<<<(N_NODES + 3) / 4, 256, 0, stream>>>(offs, esort, row, z, h, out, exatt);
}

// Round 2
// 554.872 us; speedup vs baseline: 1.9500x; 1.9500x over previous
//
#include <hip/hip_runtime.h>
#include <hip/hip_bf16.h>

#define N_NODES 50000
#define N_EDGES 800000
#define IN_F 256
#define OUT_F 32
#define NHEAD 8
#define HD 256      // NHEAD*OUT_F
#define EDGE_F 32
#define N_ETYPES 8
#define NEG_SLOPE 0.1f

// ---- tiny: he[t][hh] = sum_f a_e[hh,f] * (edge_emb @ W_e)[t, hh*32+f] ----
__global__ void edge_he_kernel(const float* __restrict__ edge_emb,
                               const float* __restrict__ W_e,
                               const float* __restrict__ a_e,
                               float* __restrict__ he) {
    int tid = threadIdx.x;
    if (tid >= N_ETYPES * NHEAD) return;
    int t = tid / NHEAD, hh = tid % NHEAD;
    float acc = 0.f;
    for (int f = 0; f < EDGE_F; ++f) {
        float ev = 0.f;
        for (int k = 0; k < EDGE_F; ++k)
            ev += edge_emb[t * EDGE_F + k] * W_e[k * (EDGE_F * NHEAD) + hh * EDGE_F + f];
        acc += a_e[hh * EDGE_F + f] * ev;
    }
    he[t * NHEAD + hh] = acc;
}

// ---- h = x @ W  (fp32, 64x64 tile, 4x4 microtile), NaN guard ----
__global__ __launch_bounds__(256) void gemm_h(const float* __restrict__ x,
                                              const float* __restrict__ W,
                                              float* __restrict__ h) {
    __shared__ float As[32][64];   // As[k][m] (transposed x tile)
    __shared__ float Bs[32][64];   // Bs[k][n]
    const int row0 = blockIdx.x * 64;
    const int col0 = blockIdx.y * 64;
    const int tid = threadIdx.x;
    const int tr = tid / 16, tc = tid % 16;
    float acc[4][4] = {};
    const int am = tid >> 2;           // 0..63 (row within tile)
    const int akq = (tid & 3) * 8;     // 0,8,16,24 (k start)
    const int bk = tid >> 3;           // 0..31
    const int bnq = (tid & 7) * 8;     // 0..56

    for (int k0 = 0; k0 < IN_F; k0 += 32) {
        int grow = row0 + am;
        float4 va0, va1;
        if (grow < N_NODES) {
            va0 = *(const float4*)&x[grow * IN_F + k0 + akq];
            va1 = *(const float4*)&x[grow * IN_F + k0 + akq + 4];
        } else {
            va0 = make_float4(0.f, 0.f, 0.f, 0.f); va1 = va0;
        }
        As[akq + 0][am] = va0.x; As[akq + 1][am] = va0.y;
        As[akq + 2][am] = va0.z; As[akq + 3][am] = va0.w;
        As[akq + 4][am] = va1.x; As[akq + 5][am] = va1.y;
        As[akq + 6][am] = va1.z; As[akq + 7][am] = va1.w;

        float4 vb0 = *(const float4*)&W[(k0 + bk) * HD + col0 + bnq];
        float4 vb1 = *(const float4*)&W[(k0 + bk) * HD + col0 + bnq + 4];
        *(float4*)&Bs[bk][bnq] = vb0;
        *(float4*)&Bs[bk][bnq + 4] = vb1;
        __syncthreads();

        #pragma unroll
        for (int k = 0; k < 32; ++k) {
            float4 a4 = *(float4*)&As[k][tr * 4];
            float4 b4 = *(float4*)&Bs[k][tc * 4];
            float av[4] = {a4.x, a4.y, a4.z, a4.w};
            float bv[4] = {b4.x, b4.y, b4.z, b4.w};
            #pragma unroll
            for (int i = 0; i < 4; ++i)
                #pragma unroll
                for (int j = 0; j < 4; ++j)
                    acc[i][j] += av[i] * bv[j];
        }
        __syncthreads();
    }
    #pragma unroll
    for (int i = 0; i < 4; ++i) {
        int grow = row0 + tr * 4 + i;
        if (grow < N_NODES) {
            float vals[4];
            #pragma unroll
            for (int j = 0; j < 4; ++j) {
                float v = acc[i][j];
                vals[j] = (v != v) ? 0.f : v;   // NaN guard as in reference
            }
            *(float4*)&h[grow * HD + col0 + tc * 4] =
                make_float4(vals[0], vals[1], vals[2], vals[3]);
        }
    }
}

// ---- hl[n,hh] = a_l[hh,:].h[n,hh,:],  hr likewise ----
__global__ __launch_bounds__(256) void node_logits(const float* __restrict__ h,
                                                   const float* __restrict__ a_l,
                                                   const float* __restrict__ a_r,
                                                   float* __restrict__ hl,
                                                   float* __restrict__ hr) {
    __shared__ float sal[HD], sar[HD];
    int tid = threadIdx.x;
    sal[tid] = a_l[tid];
    sar[tid] = a_r[tid];
    __syncthreads();
    int idx = blockIdx.x * 256 + tid;
    if (idx >= N_NODES * NHEAD) return;
    int n = idx >> 3, hh = idx & 7;
    const float* hp = h + (size_t)n * HD + hh * OUT_F;
    float al = 0.f, ar = 0.f;
    #pragma unroll
    for (int d = 0; d < OUT_F; d += 4) {
        float4 v = *(const float4*)&hp[d];
        float4 l = *(const float4*)&sal[hh * OUT_F + d];
        float4 r = *(const float4*)&sar[hh * OUT_F + d];
        al += v.x * l.x + v.y * l.y + v.z * l.z + v.w * l.w;
        ar += v.x * r.x + v.y * r.y + v.z * r.z + v.w * r.w;
    }
    hl[idx] = al;
    hr[idx] = ar;
}

// ---- CSR build ----
__global__ void calc_deg(const int* __restrict__ col, int* __restrict__ deg) {
    int e = blockIdx.x * 256 + threadIdx.x;
    if (e < N_EDGES) atomicAdd(&deg[col[e]], 1);
}

__global__ void scan1(const int* __restrict__ deg, int* __restrict__ excl,
                      int* __restrict__ bsums, int n) {
    __shared__ int sm[256];
    int tid = threadIdx.x;
    int i = blockIdx.x * 256 + tid;
    int v = (i < n) ? deg[i] : 0;
    sm[tid] = v;
    __syncthreads();
    int acc = v;
    for (int off = 1; off < 256; off <<= 1) {
        int add = (tid >= off) ? sm[tid - off] : 0;
        __syncthreads();
        acc += add;
        sm[tid] = acc;
        __syncthreads();
    }
    if (i < n) excl[i] = acc - v;
    if (tid == 255) bsums[blockIdx.x] = acc;
}

__global__ void scan2(int* __restrict__ bsums, int nb) {
    __shared__ int sm[256];
    int tid = threadIdx.x;
    int v = (tid < nb) ? bsums[tid] : 0;
    sm[tid] = v;
    __syncthreads();
    int acc = v;
    for (int off = 1; off < 256; off <<= 1) {
        int add = (tid >= off) ? sm[tid - off] : 0;
        __syncthreads();
        acc += add;
        sm[tid] = acc;
        __syncthreads();
    }
    if (tid < nb) bsums[tid] = acc - v;   // exclusive
}

__global__ void scan3(int* __restrict__ offs, const int* __restrict__ bsums,
                      int n, int total) {
    int i = blockIdx.x * 256 + threadIdx.x;
    if (i < n) offs[i] += bsums[blockIdx.x];
    if (i == 0) offs[n] = total;
}

__global__ void scatter_edges(const int* __restrict__ col,
                              const int* __restrict__ offs,
                              int* __restrict__ cursor,
                              int* __restrict__ esort) {
    int e = blockIdx.x * 256 + threadIdx.x;
    if (e < N_EDGES) {
        int c = col[e];
        int pos = atomicAdd(&cursor[c], 1);
        esort[offs[c] + pos] = e;
    }
}

// ---- fused per-node softmax + aggregation: one wave per node, no atomics ----
__global__ __launch_bounds__(256) void node_fused(const int* __restrict__ offs,
                                                  const int* __restrict__ esort,
                                                  const int* __restrict__ row,
                                                  const int* __restrict__ tp,
                                                  const float* __restrict__ hl,
                                                  const float* __restrict__ hr,
                                                  const float* __restrict__ he,
                                                  const float* __restrict__ h,
                                                  float* __restrict__ out,
                                                  float* __restrict__ att) {
    int wid = threadIdx.x >> 6;
    int lane = threadIdx.x & 63;
    int n = blockIdx.x * 4 + wid;
    if (n >= N_NODES) return;
    int beg = offs[n], end = offs[n + 1];

    // phase 1/2 lane layout: slot = lane>>3 (8 edge slots), hh = lane&7
    int slot = lane >> 3, hh = lane & 7;
    float hrv = hr[n * 8 + hh];

    // pass 1: segment max per head
    float m = -INFINITY;
    for (int j = beg + slot; j < end; j += 8) {
        int e = esort[j];
        int r = row[e], t = tp[e];
        float s = hl[r * 8 + hh] + hrv + he[t * 8 + hh];
        s = s > 0.f ? s : NEG_SLOPE * s;
        m = fmaxf(m, s);
    }
    m = fmaxf(m, __shfl_xor(m, 8));
    m = fmaxf(m, __shfl_xor(m, 16));
    m = fmaxf(m, __shfl_xor(m, 32));

    // pass 2: sum of exp(s - m) per head
    float z = 0.f;
    for (int j = beg + slot; j < end; j += 8) {
        int e = esort[j];
        int r = row[e], t = tp[e];
        float s = hl[r * 8 + hh] + hrv + he[t * 8 + hh];
        s = s > 0.f ? s : NEG_SLOPE * s;
        z += __expf(s - m);
    }
    z += __shfl_xor(z, 8);
    z += __shfl_xor(z, 16);
    z += __shfl_xor(z, 32);
    float zinv = 1.0f / z;

    // phase 3 lane layout: hh3 = lane>>3, dg = lane&7 (4 floats each)
    int hh3 = lane >> 3, dg = lane & 7;
    // lane `hh3` (0..7) holds head hh3's m/zinv in phase-1/2 layout
    float m3 = __shfl(m, hh3);
    float zinv3 = __shfl(zinv, hh3);
    float hrv3 = hr[n * 8 + hh3];

    float4 acc = make_float4(0.f, 0.f, 0.f, 0.f);
    for (int j = beg; j < end; ++j) {
        int e = esort[j];
        int r = row[e], t = tp[e];
        float s = hl[r * 8 + hh3] + hrv3 + he[t * 8 + hh3];
        s = s > 0.f ? s : NEG_SLOPE * s;
        float a = __expf(s - m3) * zinv3;
        if (dg == 0) att[(size_t)e * 8 + hh3] = a;
        const float4 hv = *(const float4*)&h[(size_t)r * HD + lane * 4];
        acc.x += a * hv.x; acc.y += a * hv.y;
        acc.z += a * hv.z; acc.w += a * hv.w;
    }
    *(float4*)&out[(size_t)n * HD + lane * 4] = acc;
}

extern "C" void kernel_launch(void* const* d_in, const int* in_sizes, int n_in,
                              void* d_out, int out_size, void* d_ws, size_t ws_size,
                              hipStream_t stream) {
    const float* x        = (const float*)d_in[0];
    const float* W        = (const float*)d_in[1];
    const float* W_e      = (const float*)d_in[2];
    const float* edge_emb = (const float*)d_in[3];
    const float* a_l      = (const float*)d_in[4];
    const float* a_r      = (const float*)d_in[5];
    const float* a_e      = (const float*)d_in[6];
    const int*   row      = (const int*)d_in[7];
    const int*   col      = (const int*)d_in[8];
    const int*   tp       = (const int*)d_in[9];

    float* out = (float*)d_out;                       // [N, 256]
    float* att = out + (size_t)N_NODES * HD;          // [E, 8]

    // workspace layout (4-byte units)
    float*    h      = (float*)d_ws;                  // 12,800,000
    float*    hl     = h + 12800000;                  //    400,000
    float*    hr     = hl + 400000;                   //    400,000
    float*    he     = hr + 400000;                   //         64
    int*      deg    = (int*)(he + 64);               //     50,000  [zeroed]
    int*      cursor = deg + 50000;                   //     50,000  [zeroed]
    int*      offs   = cursor + 50000;                //     50,001
    int*      bsums  = offs + 50001;                  //        256
    int*      esort  = bsums + 256;                   //    800,000

    hipMemsetAsync(deg, 0, (size_t)(50000 + 50000) * 4, stream);

    edge_he_kernel<<<1, 64, 0, stream>>>(edge_emb, W_e, a_e, he);

    dim3 ggrid((N_NODES + 63) / 64, 4);
    gemm_h<<<ggrid, 256, 0, stream>>>(x, W, h);

    node_logits<<<(N_NODES * NHEAD + 255) / 256, 256, 0, stream>>>(h, a_l, a_r, hl, hr);

    const int EB = (N_EDGES + 255) / 256;   // 3125
    calc_deg<<<EB, 256, 0, stream>>>(col, deg);

    const int NB = (N_NODES + 255) / 256;   // 196
    scan1<<<NB, 256, 0, stream>>>(deg, offs, bsums, N_NODES);
    scan2<<<1, 256, 0, stream>>>(bsums, NB);
    scan3<<<NB, 256, 0, stream>>>(offs, bsums, N_NODES, N_EDGES);
    scatter_edges<<<EB, 256, 0, stream>>>(col, offs, cursor, esort);

    node_fused<<<(N_NODES + 3) / 4, 256, 0, stream>>>(offs, esort, row, tp,
                                                      hl, hr, he, h, out, att);
}

// Round 3
// 386.367 us; speedup vs baseline: 2.8004x; 1.4361x over previous
//
#include <hip/hip_runtime.h>
#include <hip/hip_bf16.h>

#define N_NODES 50000
#define N_EDGES 800000
#define IN_F 256
#define OUT_F 32
#define NHEAD 8
#define HD 256      // NHEAD*OUT_F
#define EDGE_F 32
#define N_ETYPES 8
#define NEG_SLOPE 0.1f
#define CAP 64      // per-node LDS s-cache depth (avg deg=16, max ~45)

typedef __attribute__((ext_vector_type(8))) short short8;
typedef __attribute__((ext_vector_type(4))) short short4_t;
typedef __attribute__((ext_vector_type(4))) float f32x4;

__device__ __forceinline__ short f2b(float f) {
    __hip_bfloat16 t = __float2bfloat16(f);
    return __builtin_bit_cast(short, t);
}
__device__ __forceinline__ float b2f(short s) {
    return __uint_as_float(((unsigned)(unsigned short)s) << 16);
}

// ---- tiny: he[t][hh] = sum_f a_e[hh,f] * (edge_emb @ W_e)[t, hh*32+f] ----
__global__ void edge_he_kernel(const float* __restrict__ edge_emb,
                               const float* __restrict__ W_e,
                               const float* __restrict__ a_e,
                               float* __restrict__ he) {
    int tid = threadIdx.x;
    if (tid >= N_ETYPES * NHEAD) return;
    int t = tid / NHEAD, hh = tid % NHEAD;
    float acc = 0.f;
    for (int f = 0; f < EDGE_F; ++f) {
        float ev = 0.f;
        for (int k = 0; k < EDGE_F; ++k)
            ev += edge_emb[t * EDGE_F + k] * W_e[k * (EDGE_F * NHEAD) + hh * EDGE_F + f];
        acc += a_e[hh * EDGE_F + f] * ev;
    }
    he[t * NHEAD + hh] = acc;
}

// ---- Wt[n][k] = bf16(W[k][n])  (256x256, tiny) ----
__global__ void cast_wt(const float* __restrict__ W, __hip_bfloat16* __restrict__ Wt) {
    int idx = blockIdx.x * 256 + threadIdx.x;
    int n = idx >> 8, k = idx & 255;
    Wt[n * 256 + k] = __float2bfloat16(W[k * 256 + n]);
}

// ---- h(bf16) = bf16(x) @ bf16(W) via MFMA; reg-resident, no LDS ----
// block = 256 thr (4 waves), BM=64 rows, BN=256 (full width, wave owns 64 cols)
__global__ __launch_bounds__(256) void gemm_h_mfma(const float* __restrict__ x,
                                                   const __hip_bfloat16* __restrict__ Wt,
                                                   __hip_bfloat16* __restrict__ h) {
    const int wave = threadIdx.x >> 6;
    const int lane = threadIdx.x & 63;
    const int row0 = blockIdx.x * 64;
    const int wn0  = wave * 64;
    const int lrow = lane & 15;     // M-row / N-col within fragment
    const int kg   = lane >> 4;     // k-group (8 contiguous k each)

    f32x4 acc[4][4];                // [mi][ni], statically unrolled only
    #pragma unroll
    for (int mi = 0; mi < 4; ++mi)
        #pragma unroll
        for (int ni = 0; ni < 4; ++ni)
            acc[mi][ni] = (f32x4){0.f, 0.f, 0.f, 0.f};

    for (int k0 = 0; k0 < IN_F; k0 += 32) {
        short8 afrag[4];
        #pragma unroll
        for (int mi = 0; mi < 4; ++mi) {
            int r = row0 + mi * 16 + lrow;
            r = r < N_NODES ? r : N_NODES - 1;   // clamp; stores are guarded
            const float* p = &x[(size_t)r * IN_F + k0 + kg * 8];
            float4 f0 = *(const float4*)p;
            float4 f1 = *(const float4*)(p + 4);
            short8 a;
            a[0] = f2b(f0.x); a[1] = f2b(f0.y); a[2] = f2b(f0.z); a[3] = f2b(f0.w);
            a[4] = f2b(f1.x); a[5] = f2b(f1.y); a[6] = f2b(f1.z); a[7] = f2b(f1.w);
            afrag[mi] = a;
        }
        short8 bfrag[4];
        #pragma unroll
        for (int ni = 0; ni < 4; ++ni) {
            int n = wn0 + ni * 16 + lrow;
            bfrag[ni] = *(const short8*)&Wt[(size_t)n * 256 + k0 + kg * 8];
        }
        #pragma unroll
        for (int mi = 0; mi < 4; ++mi)
            #pragma unroll
            for (int ni = 0; ni < 4; ++ni)
                acc[mi][ni] = __builtin_amdgcn_mfma_f32_16x16x32_bf16(
                    afrag[mi], bfrag[ni], acc[mi][ni], 0, 0, 0);
    }

    // C/D layout: col = lane&15, row = (lane>>4)*4 + reg   [m89-verified]
    #pragma unroll
    for (int mi = 0; mi < 4; ++mi) {
        #pragma unroll
        for (int r = 0; r < 4; ++r) {
            int grow = row0 + mi * 16 + (lane >> 4) * 4 + r;
            if (grow < N_NODES) {
                #pragma unroll
                for (int ni = 0; ni < 4; ++ni) {
                    float v = acc[mi][ni][r];
                    v = (v != v) ? 0.f : v;   // NaN guard per reference
                    h[(size_t)grow * HD + wn0 + ni * 16 + (lane & 15)] = __float2bfloat16(v);
                }
            }
        }
    }
}

// ---- hl[n,hh] = a_l[hh,:].h[n,hh,:],  hr likewise (bf16 h) ----
__global__ __launch_bounds__(256) void node_logits(const __hip_bfloat16* __restrict__ h,
                                                   const float* __restrict__ a_l,
                                                   const float* __restrict__ a_r,
                                                   float* __restrict__ hl,
                                                   float* __restrict__ hr) {
    __shared__ float sal[HD], sar[HD];
    int tid = threadIdx.x;
    sal[tid] = a_l[tid];
    sar[tid] = a_r[tid];
    __syncthreads();
    int idx = blockIdx.x * 256 + tid;
    if (idx >= N_NODES * NHEAD) return;
    int n = idx >> 3, hh = idx & 7;
    const __hip_bfloat16* hp = h + (size_t)n * HD + hh * OUT_F;
    float al = 0.f, ar = 0.f;
    #pragma unroll
    for (int d0 = 0; d0 < OUT_F; d0 += 8) {
        short8 v = *(const short8*)&hp[d0];
        #pragma unroll
        for (int j = 0; j < 8; ++j) {
            float f = b2f(v[j]);
            al += f * sal[hh * OUT_F + d0 + j];
            ar += f * sar[hh * OUT_F + d0 + j];
        }
    }
    hl[idx] = al;
    hr[idx] = ar;
}

// ---- CSR build (pos saved from first atomic pass; scatter has no atomics) ----
__global__ void calc_deg(const int* __restrict__ col, int* __restrict__ deg,
                         int* __restrict__ pos) {
    int e = blockIdx.x * 256 + threadIdx.x;
    if (e < N_EDGES) pos[e] = atomicAdd(&deg[col[e]], 1);
}

__global__ void scan1(const int* __restrict__ deg, int* __restrict__ excl,
                      int* __restrict__ bsums, int n) {
    __shared__ int sm[256];
    int tid = threadIdx.x;
    int i = blockIdx.x * 256 + tid;
    int v = (i < n) ? deg[i] : 0;
    sm[tid] = v;
    __syncthreads();
    int acc = v;
    for (int off = 1; off < 256; off <<= 1) {
        int add = (tid >= off) ? sm[tid - off] : 0;
        __syncthreads();
        acc += add;
        sm[tid] = acc;
        __syncthreads();
    }
    if (i < n) excl[i] = acc - v;
    if (tid == 255) bsums[blockIdx.x] = acc;
}

__global__ void scan2(int* __restrict__ bsums, int nb) {
    __shared__ int sm[256];
    int tid = threadIdx.x;
    int v = (tid < nb) ? bsums[tid] : 0;
    sm[tid] = v;
    __syncthreads();
    int acc = v;
    for (int off = 1; off < 256; off <<= 1) {
        int add = (tid >= off) ? sm[tid - off] : 0;
        __syncthreads();
        acc += add;
        sm[tid] = acc;
        __syncthreads();
    }
    if (tid < nb) bsums[tid] = acc - v;   // exclusive
}

__global__ void scan3(int* __restrict__ offs, const int* __restrict__ bsums,
                      int n, int total) {
    int i = blockIdx.x * 256 + threadIdx.x;
    if (i < n) offs[i] += bsums[blockIdx.x];
    if (i == 0) offs[n] = total;
}

__global__ void scatter_edges(const int* __restrict__ col,
                              const int* __restrict__ offs,
                              const int* __restrict__ pos,
                              int* __restrict__ esort) {
    int e = blockIdx.x * 256 + threadIdx.x;
    if (e < N_EDGES) esort[offs[col[e]] + pos[e]] = e;
}

// ---- fused per-node softmax + aggregation: one wave/node, online m,z, s-cache ----
__global__ __launch_bounds__(256) void node_fused(const int* __restrict__ offs,
                                                  const int* __restrict__ esort,
                                                  const int* __restrict__ row,
                                                  const int* __restrict__ tp,
                                                  const float* __restrict__ hl,
                                                  const float* __restrict__ hr,
                                                  const float* __restrict__ he,
                                                  const __hip_bfloat16* __restrict__ h,
                                                  float* __restrict__ out,
                                                  float* __restrict__ att) {
    __shared__ float sc[4][CAP][8];
    int wid = threadIdx.x >> 6;
    int lane = threadIdx.x & 63;
    int n = blockIdx.x * 4 + wid;
    if (n >= N_NODES) return;
    int beg = offs[n], end = offs[n + 1], deg = end - beg;

    // pass A: online (m,z) per head; lanes = 8 slots x 8 heads; cache s in LDS
    int slot = lane >> 3, hh = lane & 7;
    float hrv = hr[n * 8 + hh];
    float m = -1e30f, z = 0.f;
    for (int jj = slot; jj < deg; jj += 8) {
        int e = esort[beg + jj];
        int r = row[e], t = tp[e];
        float s = hl[r * 8 + hh] + hrv + he[t * 8 + hh];
        s = s > 0.f ? s : NEG_SLOPE * s;
        if (jj < CAP) sc[wid][jj][hh] = s;
        if (s > m) { z = z * __expf(m - s) + 1.f; m = s; }
        else       { z += __expf(s - m); }
    }
    // merge 8 slots (fixed head) via xor 8,16,32
    {
        float mo, zo, M;
        mo = __shfl_xor(m, 8);  zo = __shfl_xor(z, 8);
        M = fmaxf(m, mo); z = z * __expf(m - M) + zo * __expf(mo - M); m = M;
        mo = __shfl_xor(m, 16); zo = __shfl_xor(z, 16);
        M = fmaxf(m, mo); z = z * __expf(m - M) + zo * __expf(mo - M); m = M;
        mo = __shfl_xor(m, 32); zo = __shfl_xor(z, 32);
        M = fmaxf(m, mo); z = z * __expf(m - M) + zo * __expf(mo - M); m = M;
    }
    float zinv = 1.0f / z;

    // pass B: lane = head(lane>>3) x 4-col group; gather bf16 h rows
    int hh3 = lane >> 3, dg = lane & 7;
    float m3 = __shfl(m, hh3);        // lane hh3 holds head hh3's merged stats
    float zinv3 = __shfl(zinv, hh3);
    float hrv3 = __shfl(hrv, hh3);

    float4 acc = make_float4(0.f, 0.f, 0.f, 0.f);
    for (int jj = 0; jj < deg; ++jj) {
        int e = esort[beg + jj];
        int r = row[e];
        float s;
        if (jj < CAP) {
            s = sc[wid][jj][hh3];
        } else {
            int t = tp[e];
            s = hl[r * 8 + hh3] + hrv3 + he[t * 8 + hh3];
            s = s > 0.f ? s : NEG_SLOPE * s;
        }
        float a = __expf(s - m3) * zinv3;
        if (dg == 0) att[(size_t)e * 8 + hh3] = a;
        short4_t hv = *(const short4_t*)&h[(size_t)r * HD + lane * 4];
        acc.x += a * b2f(hv[0]);
        acc.y += a * b2f(hv[1]);
        acc.z += a * b2f(hv[2]);
        acc.w += a * b2f(hv[3]);
    }
    *(float4*)&out[(size_t)n * HD + lane * 4] = acc;
}

extern "C" void kernel_launch(void* const* d_in, const int* in_sizes, int n_in,
                              void* d_out, int out_size, void* d_ws, size_t ws_size,
                              hipStream_t stream) {
    const float* x        = (const float*)d_in[0];
    const float* W        = (const float*)d_in[1];
    const float* W_e      = (const float*)d_in[2];
    const float* edge_emb = (const float*)d_in[3];
    const float* a_l      = (const float*)d_in[4];
    const float* a_r      = (const float*)d_in[5];
    const float* a_e      = (const float*)d_in[6];
    const int*   row      = (const int*)d_in[7];
    const int*   col      = (const int*)d_in[8];
    const int*   tp       = (const int*)d_in[9];

    float* out = (float*)d_out;                       // [N, 256] f32
    float* att = out + (size_t)N_NODES * HD;          // [E, 8]   f32

    // workspace layout (4-byte units unless noted)
    __hip_bfloat16* h  = (__hip_bfloat16*)d_ws;       // 12,800,000 bf16 (6.4M words)
    float* hl          = (float*)(h + 12800000);      //    400,000
    float* hr          = hl + 400000;                 //    400,000
    float* he          = hr + 400000;                 //         64
    __hip_bfloat16* Wt = (__hip_bfloat16*)(he + 64);  //     65,536 bf16 (32,768 words)
    int*   deg         = (int*)(Wt + 65536);          //     50,000  [zeroed]
    int*   offs        = deg + 50000;                 //     50,001
    int*   bsums       = offs + 50001;                //        256
    int*   pos         = bsums + 256;                 //    800,000
    int*   esort       = pos + 800000;                //    800,000

    hipMemsetAsync(deg, 0, (size_t)50000 * 4, stream);

    edge_he_kernel<<<1, 64, 0, stream>>>(edge_emb, W_e, a_e, he);
    cast_wt<<<256, 256, 0, stream>>>(W, Wt);

    gemm_h_mfma<<<(N_NODES + 63) / 64, 256, 0, stream>>>(x, Wt, h);

    node_logits<<<(N_NODES * NHEAD + 255) / 256, 256, 0, stream>>>(h, a_l, a_r, hl, hr);

    const int EB = (N_EDGES + 255) / 256;   // 3125
    calc_deg<<<EB, 256, 0, stream>>>(col, deg, pos);

    const int NB = (N_NODES + 255) / 256;   // 196
    scan1<<<NB, 256, 0, stream>>>(deg, offs, bsums, N_NODES);
    scan2<<<1, 256, 0, stream>>>(bsums, NB);
    scan3<<<NB, 256, 0, stream>>>(offs, bsums, N_NODES, N_EDGES);
    scatter_edges<<<EB, 256, 0, stream>>>(col, offs, pos, esort);

    node_fused<<<(N_NODES + 3) / 4, 256, 0, stream>>>(offs, esort, row, tp,
                                                      hl, hr, he, h, out, att);
}